// Round 3
// baseline (58.197 us; speedup 1.0000x reference)
//
#include <hip/hip_runtime.h>
#include <math.h>

#define NQ     12
#define DIM    4096
#define DEPTH  6
#define NBATCH 256

// ---------------------------------------------------------------------------
// Algebra: CNOT-ladder perm is the Gray map g(j) = j ^ (j>>1), linear on GF(2)^12.
// Never permute the stored state. Depth-d gates on logical bit b become
// butterflies on XOR-axis  V = A^d e_b  with role selector = row b of A^{-d},
// where A(m) = m ^ (m>>1). Since S^12 = 0, A^16 = I, so A^{-d} = A^{16-d}.
// Observables (logical bits 11,10,9 after 6 perms) reduce to stored-index
// parity masks 0x800, 0x400, 0xA00 — i.e. lane bits only.
// Layout: stored index j = (lane << 6) | reg, one wave per batch element,
// 64 f32 state registers per lane. 36 gates are pure-register butterflies,
// 36 are one shfl_xor per element. No LDS, no barriers.
//
// Round-3 fix: the lane-crossing path previously materialized pr[64]
// (128 live floats -> scratch spill, VGPR_Count=60, FETCH 739KB). Now the
// butterfly is processed pairwise with <=2 shuffle temps live at a time.
// ---------------------------------------------------------------------------

__host__ __device__ constexpr unsigned axmask(int d, int b) {
    unsigned m = 1u << b;
    for (int i = 0; i < d; ++i) m = (m ^ (m >> 1)) & 0xFFFu;
    return m;
}
__host__ __device__ constexpr unsigned selmask(int d, int b) {
    // row b of A^{-d} = (A^T)^{16-d} applied to e_b;  A^T(m) = m ^ (m<<1)
    unsigned m = 1u << b;
    for (int i = 0; i < 16 - d; ++i) m = (m ^ ((m << 1) & 0xFFFu)) & 0xFFFu;
    return m;
}

template<int D, int B>
__device__ __forceinline__ void apply_gate(float (&st)[64], float c, float s, int lane) {
    constexpr unsigned V  = axmask(D, B);
    constexpr unsigned M  = selmask(D, B);
    constexpr int VH = (int)(V >> 6), VL = (int)(V & 63u);
    constexpr unsigned MH = M >> 6, ML = M & 63u;

    // lane-parity part of the sign: se(j) = (popc(M&j)&1) ? +s : -s
    float sp = (__popc(MH & (unsigned)lane) & 1) ? s : -s;

    if constexpr (VH == 0) {
        // pure-register butterfly: pairs (r, r^VL)
        #pragma unroll
        for (int r = 0; r < 64; ++r) {
            const int r2 = r ^ VL;
            if (r2 > r) {
                float a0 = st[r], a1 = st[r2];
                float se0 = (__popc(ML & (unsigned)r)  & 1) ? -sp : sp;
                float se1 = (__popc(ML & (unsigned)r2) & 1) ? -sp : sp;
                st[r]  = fmaf(c, a0, se0 * a1);
                st[r2] = fmaf(c, a1, se1 * a0);
            }
        }
    } else if constexpr (VL == 0) {
        // pure lane-crossing: partner is same reg index in lane^VH
        #pragma unroll
        for (int r = 0; r < 64; ++r) {
            float p  = __shfl_xor(st[r], VH, 64);
            float se = (__popc(ML & (unsigned)r) & 1) ? -sp : sp;
            st[r] = fmaf(c, st[r], se * p);
        }
    } else {
        // mixed: partner = (lane^VH, r^VL); pairwise, 2 temps live
        #pragma unroll
        for (int r = 0; r < 64; ++r) {
            const int r2 = r ^ VL;
            if (r2 > r) {
                float p0 = __shfl_xor(st[r2], VH, 64);  // partner value for st[r]
                float p1 = __shfl_xor(st[r],  VH, 64);  // partner value for st[r2]
                float se0 = (__popc(ML & (unsigned)r)  & 1) ? -sp : sp;
                float se1 = (__popc(ML & (unsigned)r2) & 1) ? -sp : sp;
                st[r]  = fmaf(c, st[r],  se0 * p0);
                st[r2] = fmaf(c, st[r2], se1 * p1);
            }
        }
    }
}

__global__ void prep_kernel(const float* __restrict__ thetas, float2* __restrict__ cs) {
    int t = threadIdx.x;
    if (t < DEPTH * NQ) {
        float h = thetas[t] * 0.5f;
        cs[t] = make_float2(cosf(h), sinf(h));
    }
}

__global__ __launch_bounds__(64, 1)
void qnet_kernel(const float* __restrict__ x,      // [NBATCH, NQ]
                 const float2* __restrict__ cs,    // [DEPTH*NQ] (cos,sin)
                 float* __restrict__ out)          // [NBATCH, 3]
{
    const int b    = blockIdx.x;
    const int lane = threadIdx.x;   // 0..63

    // ---- encoder trig (wave-uniform values) ----
    float cq[12], sq[12];
    #pragma unroll
    for (int q = 0; q < 12; ++q) {
        float h = x[b * 12 + q] * 1.57079632679489662f;  // pi/2 * x
        sq[q] = sinf(h);
        cq[q] = cosf(h);
    }

    // ---- product state: st[r] for j = (lane<<6)|r ----
    // j bit (6+i) = lane bit i  <-> qubit 5-i ; j bit i = reg bit i <-> qubit 11-i
    float la = 1.0f;
    #pragma unroll
    for (int i = 0; i < 6; ++i)
        la *= ((lane >> i) & 1) ? sq[5 - i] : cq[5 - i];

    float st[64];
    st[0] = la;
    #pragma unroll
    for (int i = 0; i < 6; ++i) {
        #pragma unroll
        for (int k = 0; k < (1 << i); ++k) {
            float base = st[k];
            st[k + (1 << i)] = base * sq[11 - i];
            st[k]            = base * cq[11 - i];
        }
    }

    // ---- 6 depths x 12 gates, all in registers/shuffles ----
    // gate for qubit Q at depth D acts on logical bit 11-Q, theta cs[D*12+Q]
    #define GATE(D, Q) do { float2 cs_ = cs[(D)*12 + (Q)]; \
                            apply_gate<D, 11-(Q)>(st, cs_.x, cs_.y, lane); } while (0)
    #define DEPTH_GATES(D) \
        GATE(D,0); GATE(D,1); GATE(D,2);  GATE(D,3);  GATE(D,4);  GATE(D,5); \
        GATE(D,6); GATE(D,7); GATE(D,8);  GATE(D,9);  GATE(D,10); GATE(D,11)
    DEPTH_GATES(0);
    DEPTH_GATES(1);
    DEPTH_GATES(2);
    DEPTH_GATES(3);
    DEPTH_GATES(4);
    DEPTH_GATES(5);
    #undef DEPTH_GATES
    #undef GATE

    // ---- observer ----
    // sign masks on stored index: q0 -> bit11 (lane b5), q1 -> bit10 (lane b4),
    // q2 -> bits 9^11 (lane b3 ^ b5). Per-lane probability sum first.
    float tot = 0.0f;
    #pragma unroll
    for (int r = 0; r < 64; ++r)
        tot = fmaf(st[r], st[r], tot);

    float a0 = ((lane >> 5) & 1)                 ? -tot : tot;
    float a1 = ((lane >> 4) & 1)                 ? -tot : tot;
    float a2 = (((lane >> 3) ^ (lane >> 5)) & 1) ? -tot : tot;

    #pragma unroll
    for (int off = 32; off; off >>= 1) {
        a0 += __shfl_xor(a0, off, 64);
        a1 += __shfl_xor(a1, off, 64);
        a2 += __shfl_xor(a2, off, 64);
    }
    if (lane == 0) {
        out[b * 3 + 0] = a0;
        out[b * 3 + 1] = a1;
        out[b * 3 + 2] = a2;
    }
}

extern "C" void kernel_launch(void* const* d_in, const int* in_sizes, int n_in,
                              void* d_out, int out_size, void* d_ws, size_t ws_size,
                              hipStream_t stream) {
    (void)in_sizes; (void)n_in; (void)out_size; (void)ws_size;
    const float* x      = (const float*)d_in[0];   // [256,12] f32
    const float* thetas = (const float*)d_in[1];   // [6,12]   f32
    float* out          = (float*)d_out;           // [256,3]  f32
    float2* cs          = (float2*)d_ws;           // 72 * 8B scratch

    prep_kernel<<<dim3(1), dim3(128), 0, stream>>>(thetas, cs);
    qnet_kernel<<<dim3(NBATCH), dim3(64), 0, stream>>>(x, cs, out);
}

// Round 4
// 19.517 us; speedup vs baseline: 2.9818x; 2.9818x over previous
//
#include <hip/hip_runtime.h>
#include <math.h>
#include <type_traits>

#define NQ     12
#define DIM    4096
#define DEPTH  6
#define NBATCH 256
#define NT     256     // 4 waves per block
#define NREG   16      // state elements per thread

// ---------------------------------------------------------------------------
// CNOT-ladder perm = Gray map g(j)=j^(j>>1), linear over GF(2)^12. Fold all
// permutations into the gates: depth-d gate on logical bit b is a butterfly
// on XOR-axis V = A^d e_b with sign selector M = row b of A^{-d} (A^16 = I).
// Storage: j = (tid<<4) | r  (256 threads x 16 regs). Axis top bit = b:
//   b<=3  -> pure-register butterfly
//   4..9  -> intra-wave shuffle (j bits 4..9 are lane bits)
//   10,11 -> cross-wave exchange via double-buffered LDS (2 per depth)
// Observables reduce to stored-index parity masks 0x800,0x400,0xA00 -> tid bits.
//
// Round-4 fix: rounds 2-3 spilled st[64] to scratch (VGPR=52, latency-bound).
// Now 16 regs/thread and ALL state indexing is template-recursive static_for
// (integral_constant indices) -> guaranteed constant indices, SROA promotes.
// ---------------------------------------------------------------------------

__host__ __device__ constexpr unsigned axmask(int d, int b) {
    unsigned m = 1u << b;
    for (int i = 0; i < d; ++i) m = (m ^ (m >> 1)) & 0xFFFu;
    return m;
}
__host__ __device__ constexpr unsigned selmask(int d, int b) {
    // row b of A^{-d} = (A^T)^{16-d} e_b;  A^T(m) = m ^ (m<<1)
    unsigned m = 1u << b;
    for (int i = 0; i < 16 - d; ++i) m = (m ^ ((m << 1) & 0xFFFu)) & 0xFFFu;
    return m;
}
__host__ __device__ constexpr int cpopc(unsigned v) {
    int c = 0; while (v) { c += (int)(v & 1u); v >>= 1; } return c;
}

template<int I, int N, class F>
__device__ __forceinline__ void sfor(F&& f) {
    if constexpr (I < N) {
        f(std::integral_constant<int, I>{});
        sfor<I + 1, N>(static_cast<F&&>(f));
    }
}

template<int D, int B>
__device__ __forceinline__ void gate(float (&st)[NREG], const int tid,
                                     const float* __restrict__ gcs,
                                     float* __restrict__ lds) {
    constexpr unsigned V  = axmask(D, B);
    constexpr unsigned M  = selmask(D, B);
    constexpr int      VR = (int)(V & 15u);   // reg-bit part of axis
    constexpr int      VT = (int)(V >> 4);    // thread-bit part (lane6|wave2)
    constexpr unsigned MR = M & 15u;
    constexpr unsigned MT = M >> 4;

    const float c = gcs[2 * (D * 12 + (11 - B)) + 0];
    const float s = gcs[2 * (D * 12 + (11 - B)) + 1];
    // sign(j) = parity(M&j) ? +s : -s ; thread part at runtime, reg part constexpr
    const float sp = (__popc(MT & (unsigned)tid) & 1) ? s : -s;

    if constexpr (VT == 0) {
        // ---- pure-register butterfly ----
        sfor<0, NREG>([&](auto RC) {
            constexpr int r = RC.value, r2 = r ^ VR;
            if constexpr (r2 > r) {
                constexpr bool p0 = (cpopc(MR & (unsigned)r)  & 1) != 0;
                constexpr bool p1 = (cpopc(MR & (unsigned)r2) & 1) != 0;
                float a0 = st[r], a1 = st[r2];
                float t0 = sp * a1, t1 = sp * a0;
                st[r]  = fmaf(c, a0, p0 ? -t0 : t0);
                st[r2] = fmaf(c, a1, p1 ? -t1 : t1);
            }
        });
    } else if constexpr ((VT >> 6) == 0) {
        // ---- intra-wave shuffle butterfly ----
        if constexpr (VR == 0) {
            sfor<0, NREG>([&](auto RC) {
                constexpr int r = RC.value;
                constexpr bool pr_ = (cpopc(MR & (unsigned)r) & 1) != 0;
                float p = __shfl_xor(st[r], VT, 64);
                float t = sp * p;
                st[r] = fmaf(c, st[r], pr_ ? -t : t);
            });
        } else {
            sfor<0, NREG>([&](auto RC) {
                constexpr int r = RC.value, r2 = r ^ VR;
                if constexpr (r2 > r) {
                    constexpr bool p0 = (cpopc(MR & (unsigned)r)  & 1) != 0;
                    constexpr bool p1 = (cpopc(MR & (unsigned)r2) & 1) != 0;
                    float pa = __shfl_xor(st[r2], VT, 64);   // partner for r
                    float pb = __shfl_xor(st[r],  VT, 64);   // partner for r2
                    float t0 = sp * pa, t1 = sp * pb;
                    st[r]  = fmaf(c, st[r],  p0 ? -t0 : t0);
                    st[r2] = fmaf(c, st[r2], p1 ? -t1 : t1);
                }
            });
        }
    } else {
        // ---- cross-wave exchange via LDS (double-buffered, 1 barrier) ----
        constexpr int gidx = D * 2 + (11 - B);        // B in {11,10} -> even/odd
        constexpr int buf  = (gidx & 1) * DIM;
        const int base = buf + tid * 16;
        const int sw   = ((tid >> 1) & 3) << 2;       // bank-spread swizzle
        sfor<0, 4>([&](auto KC) {
            constexpr int k = KC.value;
            float4 v = make_float4(st[4*k], st[4*k+1], st[4*k+2], st[4*k+3]);
            *reinterpret_cast<float4*>(&lds[base + ((k << 2) ^ sw)]) = v;
        });
        __syncthreads();
        const int ptid  = tid ^ VT;
        const int pbase = buf + ptid * 16;
        const int psw   = ((ptid >> 1) & 3) << 2;
        sfor<0, 4>([&](auto KC) {
            constexpr int k  = KC.value;
            constexpr int pc = k ^ (VR >> 2);
            float4 pv = *reinterpret_cast<const float4*>(&lds[pbase + ((pc << 2) ^ psw)]);
            sfor<0, 4>([&](auto EC) {
                constexpr int e  = EC.value;
                constexpr int r  = 4 * k + e;
                constexpr int pe = e ^ (VR & 3);
                constexpr bool pr_ = (cpopc(MR & (unsigned)r) & 1) != 0;
                float p = (pe == 0) ? pv.x : (pe == 1) ? pv.y : (pe == 2) ? pv.z : pv.w;
                float t = sp * p;
                st[r] = fmaf(c, st[r], pr_ ? -t : t);
            });
        });
    }
}

__global__ __launch_bounds__(NT, 1)
void qnet_kernel(const float* __restrict__ x,       // [NBATCH, NQ]
                 const float* __restrict__ thetas,  // [DEPTH, NQ]
                 float* __restrict__ out)           // [NBATCH, 3]
{
    __shared__ __align__(16) float lds[2 * DIM];    // 32 KB exchange buffers
    __shared__ float gcs[72 * 2];                   // gate (cos,sin) pairs
    __shared__ float red[12];                       // 4 waves x 3 observables

    const int b   = blockIdx.x;
    const int tid = threadIdx.x;

    // gate trig table (wave-uniform broadcast reads later)
    if (tid < 72) {
        float h = thetas[tid] * 0.5f;
        gcs[2 * tid + 0] = cosf(h);
        gcs[2 * tid + 1] = sinf(h);
    }

    // ---- encoder: per-thread sincos + product state ----
    float cq[12], sq[12];
    sfor<0, 12>([&](auto QC) {
        constexpr int q = QC.value;
        float h = x[b * 12 + q] * 1.57079632679489662f;   // pi/2 * x
        sq[q] = sinf(h);
        cq[q] = cosf(h);
    });

    // j = (tid<<4) | r ; j bit (4+i) = tid bit i <-> qubit 7-i ; j bit i (i<4) <-> qubit 11-i
    float la = 1.0f;
    sfor<0, 8>([&](auto IC) {
        constexpr int i = IC.value;
        la *= ((tid >> i) & 1) ? sq[7 - i] : cq[7 - i];
    });

    float st[NREG];
    st[0] = la;
    sfor<0, 4>([&](auto IC) {
        constexpr int i = IC.value;
        sfor<0, (1 << i)>([&](auto KC) {
            constexpr int k = KC.value;
            float base = st[k];
            st[k + (1 << i)] = base * sq[11 - i];
            st[k]            = base * cq[11 - i];
        });
    });

    __syncthreads();   // gcs table ready

    // ---- 6 depths x 12 gates ----
    sfor<0, 6>([&](auto DC) {
        constexpr int D = DC.value;
        sfor<0, 12>([&](auto QC) {
            constexpr int Q = QC.value;
            gate<D, 11 - Q>(st, tid, gcs, lds);
        });
    });

    // ---- observer: masks 0x800,0x400,0xA00 -> tid bits 7 / 6 / 7^5 ----
    float tot = 0.0f;
    sfor<0, NREG>([&](auto RC) {
        constexpr int r = RC.value;
        tot = fmaf(st[r], st[r], tot);
    });

    float a0 = ((tid >> 7) & 1)                 ? -tot : tot;
    float a1 = ((tid >> 6) & 1)                 ? -tot : tot;
    float a2 = (((tid >> 7) ^ (tid >> 5)) & 1)  ? -tot : tot;

    #pragma unroll
    for (int off = 32; off; off >>= 1) {
        a0 += __shfl_xor(a0, off, 64);
        a1 += __shfl_xor(a1, off, 64);
        a2 += __shfl_xor(a2, off, 64);
    }
    const int lane = tid & 63, w = tid >> 6;
    if (lane == 0) {
        red[w * 3 + 0] = a0;
        red[w * 3 + 1] = a1;
        red[w * 3 + 2] = a2;
    }
    __syncthreads();
    if (tid < 3)
        out[b * 3 + tid] = red[tid] + red[3 + tid] + red[6 + tid] + red[9 + tid];
}

extern "C" void kernel_launch(void* const* d_in, const int* in_sizes, int n_in,
                              void* d_out, int out_size, void* d_ws, size_t ws_size,
                              hipStream_t stream) {
    (void)in_sizes; (void)n_in; (void)out_size; (void)d_ws; (void)ws_size;
    const float* x      = (const float*)d_in[0];   // [256,12] f32
    const float* thetas = (const float*)d_in[1];   // [6,12]   f32
    float* out          = (float*)d_out;           // [256,3]  f32

    qnet_kernel<<<dim3(NBATCH), dim3(NT), 0, stream>>>(x, thetas, out);
}

// Round 5
// 16.056 us; speedup vs baseline: 3.6247x; 1.2156x over previous
//
#include <hip/hip_runtime.h>
#include <math.h>
#include <type_traits>

#define NQ     12
#define DIM    4096
#define DEPTH  6
#define NBATCH 256
#define NT     256     // 4 waves per block
#define NREG   16      // state elements per thread

// ---------------------------------------------------------------------------
// CNOT-ladder perm = Gray map g(j)=j^(j>>1), linear over GF(2)^12. Fold all
// permutations into the gates: depth-d gate on logical bit b is a butterfly
// on XOR-axis V = A^d e_b with sign selector M = row b of A^{-d} (A^16 = I):
//   new[j] = c*old[j] + eps(j)*s*old[j^V],  eps(j) = parity(M&j) ? +1 : -1
// Storage: j = (tid<<4) | r  (256 threads x 16 regs).
//   b<=3          -> pure-register butterfly (V,M reg bits known constexpr)
//   b=4..9        -> intra-wave lane xor: DPP (masks 1,2,3,7,15), ds_swizzle
//                    (<32), or shfl_xor (>=32). M has no reg bits (b>=4).
//   b=10,11       -> cross-wave. V,M are PURELY thread bits for all D<=5
//                    (static_asserted). The two gates of each depth are FUSED
//                    into one 4-term LDS exchange (1 barrier/depth, 6 total):
//     w[j] = c1c2*psi + c2s1*e1*psi^T1 + c1s2*e2*psi^T2 + s1s2*e1e2*psi^T1^T2
//                    (parity(M1&V2) = (A^-D A^D)[11][10] = 0 makes kC exact.)
// Observables reduce to stored-index parity masks 0x800,0x400,0xA00 (tid bits).
// Trig: v_sin/v_cos take REVOLUTIONS: sin(x*pi/2)=v_sin(0.25x),
//       sin(theta/2)=v_sin(theta/(4pi)).
// ---------------------------------------------------------------------------

__host__ __device__ constexpr unsigned axmask(int d, int b) {
    unsigned m = 1u << b;
    for (int i = 0; i < d; ++i) m = (m ^ (m >> 1)) & 0xFFFu;
    return m;
}
__host__ __device__ constexpr unsigned selmask(int d, int b) {
    // row b of A^{-d} = (A^T)^{16-d} e_b;  A^T(m) = m ^ (m<<1)
    unsigned m = 1u << b;
    for (int i = 0; i < 16 - d; ++i) m = (m ^ ((m << 1) & 0xFFFu)) & 0xFFFu;
    return m;
}
__host__ __device__ constexpr int cpopc(unsigned v) {
    int c = 0; while (v) { c += (int)(v & 1u); v >>= 1; } return c;
}

template<int I, int N, class F>
__device__ __forceinline__ void sfor(F&& f) {
    if constexpr (I < N) {
        f(std::integral_constant<int, I>{});
        sfor<I + 1, N>(static_cast<F&&>(f));
    }
}

// ---- lane-xor primitive: DPP > ds_swizzle > bpermute, by mask ----
template<int MASK>
__device__ __forceinline__ float lxor(float v) {
    static_assert(MASK > 0 && MASK < 64, "lane mask");
    if constexpr (MASK == 1 || MASK == 2 || MASK == 3 || MASK == 7 || MASK == 15) {
        constexpr int ctrl = (MASK == 1) ? 0xB1     // quad_perm(1,0,3,2)
                           : (MASK == 2) ? 0x4E     // quad_perm(2,3,0,1)
                           : (MASK == 3) ? 0x1B     // quad_perm(3,2,1,0)
                           : (MASK == 7) ? 0x141    // row_half_mirror (xor7)
                           :               0x140;   // row_mirror      (xor15)
        int iv = __float_as_int(v);
        return __int_as_float(__builtin_amdgcn_update_dpp(iv, iv, ctrl, 0xF, 0xF, false));
    } else if constexpr (MASK < 32) {
        // ds_swizzle BitMode: (xor<<10) | (or<<5) | and(0x1F)
        return __int_as_float(__builtin_amdgcn_ds_swizzle(__float_as_int(v),
                                                          (MASK << 10) | 0x1F));
    } else {
        return __shfl_xor(v, MASK, 64);
    }
}

// ---- pure-register gate (b<=3) ----
template<int D, int B>
__device__ __forceinline__ void gate_reg(float (&st)[NREG], const int tid,
                                         float c, float s) {
    constexpr unsigned V = axmask(D, B), M = selmask(D, B);
    constexpr int VR = (int)(V & 15u);
    static_assert((V >> 4) == 0, "reg gate");
    constexpr unsigned MR = M & 15u, MT = M >> 4;
    const float sp = (__popc(MT & (unsigned)tid) & 1) ? s : -s;
    sfor<0, NREG>([&](auto RC) {
        constexpr int r = RC.value, r2 = r ^ VR;
        if constexpr (r2 > r) {
            constexpr bool p0 = (cpopc(MR & (unsigned)r)  & 1) != 0;
            constexpr bool p1 = (cpopc(MR & (unsigned)r2) & 1) != 0;
            float a0 = st[r], a1 = st[r2];
            float t0 = sp * a1, t1 = sp * a0;
            st[r]  = fmaf(c, a0, p0 ? -t0 : t0);
            st[r2] = fmaf(c, a1, p1 ? -t1 : t1);
        }
    });
}

// ---- intra-wave lane-crossing gate (b=4..9) ----
template<int D, int B>
__device__ __forceinline__ void gate_shfl(float (&st)[NREG], const int tid,
                                          float c, float s) {
    constexpr unsigned V = axmask(D, B), M = selmask(D, B);
    constexpr int VT = (int)(V >> 4), VR = (int)(V & 15u);
    static_assert(VT > 0 && (VT >> 6) == 0, "intra-wave gate");
    static_assert((M & 15u) == 0, "mask has no reg bits for b>=4");
    const float sp = (__popc((M >> 4) & (unsigned)tid) & 1) ? s : -s;
    if constexpr (VR == 0) {
        sfor<0, NREG>([&](auto RC) {
            constexpr int r = RC.value;
            float p = lxor<VT>(st[r]);          // SIMD-lockstep: reads pre-update
            st[r] = fmaf(c, st[r], sp * p);
        });
    } else {
        sfor<0, NREG>([&](auto RC) {
            constexpr int r = RC.value, r2 = r ^ VR;
            if constexpr (r2 > r) {
                float pa = lxor<VT>(st[r2]);    // partner for r
                float pb = lxor<VT>(st[r]);     // partner for r2
                st[r]  = fmaf(c, st[r],  sp * pa);
                st[r2] = fmaf(c, st[r2], sp * pb);
            }
        });
    }
}

// ---- fused cross-wave gate pair (b=11 then b=10), one barrier ----
template<int D>
__device__ __forceinline__ void cross2(float (&st)[NREG], const int tid,
                                       float2 cs1, float2 cs2,
                                       float* __restrict__ lds) {
    constexpr unsigned V1 = axmask(D, 11), V2 = axmask(D, 10);
    constexpr unsigned M1 = selmask(D, 11), M2 = selmask(D, 10);
    static_assert((V1 & 15u) == 0 && (V2 & 15u) == 0, "cross axes thread-pure");
    static_assert((M1 & 15u) == 0 && (M2 & 15u) == 0, "cross masks thread-pure");
    constexpr int T1 = (int)(V1 >> 4), T2 = (int)(V2 >> 4);
    static_assert((cpopc(M1 & V2) & 1) == 0, "kC sign identity");

    const float e1 = (__popc((M1 >> 4) & (unsigned)tid) & 1) ? 1.f : -1.f;
    const float e2 = (__popc((M2 >> 4) & (unsigned)tid) & 1) ? 1.f : -1.f;
    const float k0 = cs1.x * cs2.x;
    const float kA = cs1.y * cs2.x * e1;
    const float kB = cs1.x * cs2.y * e2;
    const float kC = cs1.y * cs2.y * e1 * e2;

    float* buf = lds + (D & 1) * DIM;
    const int sw = tid & 3;
    sfor<0, 4>([&](auto KC) {
        constexpr int k = KC.value;
        *reinterpret_cast<float4*>(&buf[tid * 16 + 4 * (k ^ sw)]) =
            make_float4(st[4*k], st[4*k+1], st[4*k+2], st[4*k+3]);
    });
    __syncthreads();
    const int p1 = tid ^ T1, p2 = tid ^ T2, p3 = tid ^ (T1 ^ T2);
    const int b1 = p1 * 16, s1w = p1 & 3;
    const int b2 = p2 * 16, s2w = p2 & 3;
    const int b3 = p3 * 16, s3w = p3 & 3;
    sfor<0, 4>([&](auto KC) {
        constexpr int k = KC.value;
        float4 A  = *reinterpret_cast<const float4*>(&buf[b1 + 4 * (k ^ s1w)]);
        float4 Bv = *reinterpret_cast<const float4*>(&buf[b2 + 4 * (k ^ s2w)]);
        float4 Cv = *reinterpret_cast<const float4*>(&buf[b3 + 4 * (k ^ s3w)]);
        float t;
        t = k0 * st[4*k+0]; t = fmaf(kA, A.x, t); t = fmaf(kB, Bv.x, t); st[4*k+0] = fmaf(kC, Cv.x, t);
        t = k0 * st[4*k+1]; t = fmaf(kA, A.y, t); t = fmaf(kB, Bv.y, t); st[4*k+1] = fmaf(kC, Cv.y, t);
        t = k0 * st[4*k+2]; t = fmaf(kA, A.z, t); t = fmaf(kB, Bv.z, t); st[4*k+2] = fmaf(kC, Cv.z, t);
        t = k0 * st[4*k+3]; t = fmaf(kA, A.w, t); t = fmaf(kB, Bv.w, t); st[4*k+3] = fmaf(kC, Cv.w, t);
    });
}

template<int D>
__device__ __forceinline__ void depth_apply(float (&st)[NREG], const int tid,
                                            const float2* __restrict__ gcs2,
                                            float* __restrict__ lds) {
    // hoist this depth's 12 (cos,sin) pairs (constexpr-indexed -> registers)
    float2 cs[12];
    sfor<0, 12>([&](auto QC) { cs[QC.value] = gcs2[D * 12 + QC.value]; });
    // fused cross-wave pair first (all same-depth gates commute)
    cross2<D>(st, tid, cs[0], cs[1], lds);
    // remaining gates: Q=2..11 -> b=9..0
    sfor<2, 12>([&](auto QC) {
        constexpr int Q = QC.value, B = 11 - Q;
        if constexpr (B >= 4) gate_shfl<D, B>(st, tid, cs[Q].x, cs[Q].y);
        else                  gate_reg <D, B>(st, tid, cs[Q].x, cs[Q].y);
    });
}

__global__ __launch_bounds__(NT, 1)
void qnet_kernel(const float* __restrict__ x,       // [NBATCH, NQ]
                 const float* __restrict__ thetas,  // [DEPTH, NQ]
                 float* __restrict__ out)           // [NBATCH, 3]
{
    __shared__ __align__(16) float lds[2 * DIM];    // 32 KB exchange buffers
    __shared__ float2 gcs2[72];                     // gate (cos,sin)
    __shared__ float red[12];

    const int b   = blockIdx.x;
    const int tid = threadIdx.x;

    // gate trig: v_sin/v_cos take revolutions; theta/2 rad = theta/(4pi) rev
    if (tid < 72) {
        float rev = thetas[tid] * 0.07957747154594767f;
        gcs2[tid] = make_float2(__builtin_amdgcn_cosf(rev),
                                __builtin_amdgcn_sinf(rev));
    }

    // ---- encoder: x*pi/2 rad = x/4 rev ----
    const float4* xv = reinterpret_cast<const float4*>(x + b * 12);
    float4 xa = xv[0], xb = xv[1], xc = xv[2];
    float xs[12] = {xa.x, xa.y, xa.z, xa.w, xb.x, xb.y, xb.z, xb.w,
                    xc.x, xc.y, xc.z, xc.w};
    float cq[12], sq[12];
    sfor<0, 12>([&](auto QC) {
        constexpr int q = QC.value;
        float rev = xs[q] * 0.25f;
        sq[q] = __builtin_amdgcn_sinf(rev);
        cq[q] = __builtin_amdgcn_cosf(rev);
    });

    // product state: j = (tid<<4)|r ; j bit(4+i)=tid bit i <-> qubit 7-i;
    // j bit i (i<4) <-> qubit 11-i
    float la = 1.0f;
    sfor<0, 8>([&](auto IC) {
        constexpr int i = IC.value;
        la *= ((tid >> i) & 1) ? sq[7 - i] : cq[7 - i];
    });

    float st[NREG];
    st[0] = la;
    sfor<0, 4>([&](auto IC) {
        constexpr int i = IC.value;
        sfor<0, (1 << i)>([&](auto KC) {
            constexpr int k = KC.value;
            float base = st[k];
            st[k + (1 << i)] = base * sq[11 - i];
            st[k]            = base * cq[11 - i];
        });
    });

    __syncthreads();   // gcs2 ready

    sfor<0, 6>([&](auto DC) { depth_apply<DC.value>(st, tid, gcs2, lds); });

    // ---- observer: parity masks 0x800,0x400,0xA00 -> tid bits 7 / 6 / 7^5 ----
    float tot = 0.0f;
    sfor<0, NREG>([&](auto RC) {
        constexpr int r = RC.value;
        tot = fmaf(st[r], st[r], tot);
    });

    float a0 = ((tid >> 7) & 1)                ? -tot : tot;
    float a1 = ((tid >> 6) & 1)                ? -tot : tot;
    float a2 = (((tid >> 7) ^ (tid >> 5)) & 1) ? -tot : tot;

    #pragma unroll
    for (int off = 32; off; off >>= 1) {
        a0 += __shfl_xor(a0, off, 64);
        a1 += __shfl_xor(a1, off, 64);
        a2 += __shfl_xor(a2, off, 64);
    }
    const int lane = tid & 63, w = tid >> 6;
    if (lane == 0) {
        red[w * 3 + 0] = a0;
        red[w * 3 + 1] = a1;
        red[w * 3 + 2] = a2;
    }
    __syncthreads();
    if (tid < 3)
        out[b * 3 + tid] = red[tid] + red[3 + tid] + red[6 + tid] + red[9 + tid];
}

extern "C" void kernel_launch(void* const* d_in, const int* in_sizes, int n_in,
                              void* d_out, int out_size, void* d_ws, size_t ws_size,
                              hipStream_t stream) {
    (void)in_sizes; (void)n_in; (void)out_size; (void)d_ws; (void)ws_size;
    const float* x      = (const float*)d_in[0];   // [256,12] f32
    const float* thetas = (const float*)d_in[1];   // [6,12]   f32
    float* out          = (float*)d_out;           // [256,3]  f32

    qnet_kernel<<<dim3(NBATCH), dim3(NT), 0, stream>>>(x, thetas, out);
}

// Round 7
// 15.703 us; speedup vs baseline: 3.7062x; 1.0225x over previous
//
#include <hip/hip_runtime.h>
#include <math.h>
#include <type_traits>

#define NQ     12
#define DIM    4096
#define DEPTH  6
#define NBATCH 256
#define NT     256     // 4 waves per block
#define NREG   16      // state elements per thread

// ---------------------------------------------------------------------------
// CNOT-ladder perm = Gray map g(j)=j^(j>>1), linear over GF(2)^12. All perms
// folded into gates: depth-d gate on logical bit b = butterfly on XOR-axis
// V = A^d e_b with sign selector M = row b of A^{-d} (A^16=I):
//   new[j] = x[j] + tau(j)*x[j^V],  tau = parity(M&j) ? +t : -t, t=tan(th/2)
// (tan-normalized; global scale sc=prod cos applied once in observer).
// Storage j = (tid<<4)|r. b<=3: register butterfly; b=4..9 lane-xor;
// b=10,11: fused 4-term LDS exchange, 1 barrier/depth.
//
// ROUND-7 BISECT: round 6 (absmax .445, partial corruption) introduced
// unproven cross-lane primitives (permlane16/32_swap asm, DPP row_ror:8).
// This round uses ONLY round-5-proven cross-lane ops:
//   masks 1..15  -> DPP compositions from proven ctrls {0xB1,0x4E,0x1B,
//                   0x141(half_mirror=xor7), 0x140(mirror=xor15)}
//   masks 16..31 -> ds_swizzle BitMode (proven round 5)
//   masks 32..63 -> __shfl_xor (proven rounds 1-5)
// Everything else (tan form, fused cross2, scalar thetas, S/T observer) kept.
// ---------------------------------------------------------------------------

__host__ __device__ constexpr unsigned axmask(int d, int b) {
    unsigned m = 1u << b;
    for (int i = 0; i < d; ++i) m = (m ^ (m >> 1)) & 0xFFFu;
    return m;
}
__host__ __device__ constexpr unsigned selmask(int d, int b) {
    unsigned m = 1u << b;
    for (int i = 0; i < 16 - d; ++i) m = (m ^ ((m << 1) & 0xFFFu)) & 0xFFFu;
    return m;
}
__host__ __device__ constexpr int cpopc(unsigned v) {
    int c = 0; while (v) { c += (int)(v & 1u); v >>= 1; } return c;
}

template<int I, int N, class F>
__device__ __forceinline__ void sfor(F&& f) {
    if constexpr (I < N) {
        f(std::integral_constant<int, I>{});
        sfor<I + 1, N>(static_cast<F&&>(f));
    }
}

// ---- cross-lane primitives (round-5-proven set only) ----
template<int CTRL>
__device__ __forceinline__ float dppx(float v) {
    int iv = __float_as_int(v);
    return __int_as_float(__builtin_amdgcn_update_dpp(iv, iv, CTRL, 0xF, 0xF, false));
}
// any 4-bit xor mask from proven generators {1,2,3,7,15}
template<int M4>
__device__ __forceinline__ float lxor_low(float v) {
    static_assert(M4 >= 1 && M4 <= 15, "low mask");
    if constexpr      (M4 == 1)  return dppx<0xB1>(v);    // quad_perm xor1
    else if constexpr (M4 == 2)  return dppx<0x4E>(v);    // quad_perm xor2
    else if constexpr (M4 == 3)  return dppx<0x1B>(v);    // quad_perm xor3
    else if constexpr (M4 == 7)  return dppx<0x141>(v);   // row_half_mirror
    else if constexpr (M4 == 15) return dppx<0x140>(v);   // row_mirror
    else if constexpr ((M4 & 8) == 0)   // 4,5,6 = 7 ^ {3,2,1}
        return lxor_low<M4 ^ 7>(dppx<0x141>(v));
    else                                // 8..14 = 15 ^ {7..1}
        return lxor_low<M4 ^ 15>(dppx<0x140>(v));
}
template<int MASK>
__device__ __forceinline__ float lxor(float v) {
    static_assert(MASK > 0 && MASK < 64, "lane mask");
    if constexpr (MASK >= 32) {
        return __shfl_xor(v, MASK, 64);
    } else if constexpr (MASK >= 16) {
        // ds_swizzle BitMode: (xor<<10) | (or<<5) | and(0x1F)
        return __int_as_float(__builtin_amdgcn_ds_swizzle(__float_as_int(v),
                                                          (MASK << 10) | 0x1F));
    } else {
        return lxor_low<MASK>(v);
    }
}

// ---- pure-register gate (b<=3), tan form: 1 fma/elem ----
template<int D, int B>
__device__ __forceinline__ void gate_reg(float (&st)[NREG], int tid, float t) {
    constexpr unsigned V = axmask(D, B), M = selmask(D, B);
    static_assert((V >> 4) == 0 && V != 0, "reg gate");
    constexpr int VR = (int)V;
    constexpr unsigned MR = M & 15u, MT = M >> 4;
    const float tp = (__popc(MT & (unsigned)tid) & 1) ? t : -t;
    const float tn = -tp;
    sfor<0, NREG>([&](auto RC) {
        constexpr int r = RC.value, r2 = r ^ VR;
        if constexpr (r2 > r) {
            constexpr bool p0 = (cpopc(MR & (unsigned)r)  & 1) != 0;
            constexpr bool p1 = (cpopc(MR & (unsigned)r2) & 1) != 0;
            float a0 = st[r];
            st[r]  = fmaf(p0 ? tn : tp, st[r2], st[r]);
            st[r2] = fmaf(p1 ? tn : tp, a0,     st[r2]);
        }
    });
}

// ---- intra-wave lane-crossing gate (b=4..9), tan form ----
template<int D, int B>
__device__ __forceinline__ void gate_lane(float (&st)[NREG], int tid, float t) {
    constexpr unsigned V = axmask(D, B), M = selmask(D, B);
    constexpr int VT = (int)(V >> 4), VR = (int)(V & 15u);
    static_assert(VT > 0 && VT < 64, "intra-wave gate");
    static_assert((M & 15u) == 0, "no reg bits in selector for b>=4");
    const float tp = (__popc((M >> 4) & (unsigned)tid) & 1) ? t : -t;
    if constexpr (VR == 0) {
        sfor<0, NREG>([&](auto RC) {
            constexpr int r = RC.value;
            float p = lxor<VT>(st[r]);      // SIMD-lockstep: reads pre-update
            st[r] = fmaf(tp, p, st[r]);
        });
    } else {
        sfor<0, NREG>([&](auto RC) {
            constexpr int r = RC.value, r2 = r ^ VR;
            if constexpr (r2 > r) {
                float pa = lxor<VT>(st[r2]);
                float pb = lxor<VT>(st[r]);
                st[r]  = fmaf(tp, pa, st[r]);
                st[r2] = fmaf(tp, pb, st[r2]);
            }
        });
    }
}

// ---- fused cross-wave gate pair (b=11,10), tan form: 3 fma/elem ----
template<int D>
__device__ __forceinline__ void cross2(float (&st)[NREG], int tid,
                                       float t1, float t2,
                                       float* __restrict__ lds) {
    constexpr unsigned V1 = axmask(D, 11), V2 = axmask(D, 10);
    constexpr unsigned M1 = selmask(D, 11), M2 = selmask(D, 10);
    static_assert((V1 & 15u) == 0 && (V2 & 15u) == 0, "cross axes thread-pure");
    static_assert((M1 & 15u) == 0 && (M2 & 15u) == 0, "cross masks thread-pure");
    constexpr int T1 = (int)(V1 >> 4), T2 = (int)(V2 >> 4);
    static_assert((cpopc(M1 & V2) & 1) == 0, "kC sign identity");

    const float t1p = (__popc((M1 >> 4) & (unsigned)tid) & 1) ? t1 : -t1;
    const float t2p = (__popc((M2 >> 4) & (unsigned)tid) & 1) ? t2 : -t2;
    const float t12 = t1p * t2p;

    float* buf = lds + (D & 1) * DIM;
    const int sw = tid & 3;
    sfor<0, 4>([&](auto KC) {
        constexpr int k = KC.value;
        *reinterpret_cast<float4*>(&buf[tid * 16 + 4 * (k ^ sw)]) =
            make_float4(st[4*k], st[4*k+1], st[4*k+2], st[4*k+3]);
    });
    __syncthreads();
    const int p1 = tid ^ T1, p2 = tid ^ T2, p3 = tid ^ (T1 ^ T2);
    const int b1 = p1 * 16, s1w = p1 & 3;
    const int b2 = p2 * 16, s2w = p2 & 3;
    const int b3 = p3 * 16, s3w = p3 & 3;
    sfor<0, 4>([&](auto KC) {
        constexpr int k = KC.value;
        float4 A  = *reinterpret_cast<const float4*>(&buf[b1 + 4 * (k ^ s1w)]);
        float4 Bv = *reinterpret_cast<const float4*>(&buf[b2 + 4 * (k ^ s2w)]);
        float4 Cv = *reinterpret_cast<const float4*>(&buf[b3 + 4 * (k ^ s3w)]);
        float t;
        t = fmaf(t1p, A.x, st[4*k+0]); t = fmaf(t2p, Bv.x, t); st[4*k+0] = fmaf(t12, Cv.x, t);
        t = fmaf(t1p, A.y, st[4*k+1]); t = fmaf(t2p, Bv.y, t); st[4*k+1] = fmaf(t12, Cv.y, t);
        t = fmaf(t1p, A.z, st[4*k+2]); t = fmaf(t2p, Bv.z, t); st[4*k+2] = fmaf(t12, Cv.z, t);
        t = fmaf(t1p, A.w, st[4*k+3]); t = fmaf(t2p, Bv.w, t); st[4*k+3] = fmaf(t12, Cv.w, t);
    });
}

// ---- one depth: scalar-loaded thetas -> on-the-fly tan; returns prod(c) ----
template<int D>
__device__ __forceinline__ float depth_apply(float (&st)[NREG], int tid,
                                             const float* __restrict__ thetas,
                                             float* __restrict__ lds) {
    float tq[12];
    float scd = 1.0f;
    sfor<0, 12>([&](auto QC) {
        constexpr int q = QC.value;
        float rev = thetas[D * 12 + q] * 0.07957747154594767f; // (th/2)/(2pi)
        float cc  = __builtin_amdgcn_cosf(rev);
        float ss  = __builtin_amdgcn_sinf(rev);
        tq[q] = ss * __builtin_amdgcn_rcpf(cc);
        scd  *= cc;
    });
    cross2<D>(st, tid, tq[0], tq[1], lds);
    sfor<2, 12>([&](auto QC) {
        constexpr int Q = QC.value, B = 11 - Q;
        if constexpr (B >= 4) gate_lane<D, B>(st, tid, tq[Q]);
        else                  gate_reg <D, B>(st, tid, tq[Q]);
    });
    return scd;
}

__global__ __launch_bounds__(NT, 1)
void qnet_kernel(const float* __restrict__ x,       // [NBATCH, NQ]
                 const float* __restrict__ thetas,  // [DEPTH, NQ]
                 float* __restrict__ out)           // [NBATCH, 3]
{
    __shared__ __align__(16) float lds[2 * DIM];    // 32 KB exchange buffers
    __shared__ float red[8];                        // 4 waves x {S, T}

    const int b   = blockIdx.x;
    const int tid = threadIdx.x;

    // ---- encoder: x*pi/2 rad = x/4 rev (round-5-proven) ----
    const float4* xv = reinterpret_cast<const float4*>(x + b * 12);
    float4 xa = xv[0], xb = xv[1], xc = xv[2];
    float xs[12] = {xa.x, xa.y, xa.z, xa.w, xb.x, xb.y, xb.z, xb.w,
                    xc.x, xc.y, xc.z, xc.w};
    float cq[12], sq[12];
    sfor<0, 12>([&](auto QC) {
        constexpr int q = QC.value;
        float rev = xs[q] * 0.25f;
        sq[q] = __builtin_amdgcn_sinf(rev);
        cq[q] = __builtin_amdgcn_cosf(rev);
    });

    // product state: j = (tid<<4)|r; j bit(4+i)=tid bit i <-> qubit 7-i;
    // j bit i (i<4) <-> qubit 11-i
    float la = 1.0f;
    sfor<0, 8>([&](auto IC) {
        constexpr int i = IC.value;
        la *= ((tid >> i) & 1) ? sq[7 - i] : cq[7 - i];
    });
    float st[NREG];
    st[0] = la;
    sfor<0, 4>([&](auto IC) {
        constexpr int i = IC.value;
        sfor<0, (1 << i)>([&](auto KC) {
            constexpr int k = KC.value;
            float base = st[k];
            st[k + (1 << i)] = base * sq[11 - i];
            st[k]            = base * cq[11 - i];
        });
    });

    // ---- 6 depths (LDS use inside cross2: write -> barrier -> read;
    //      depth-parity double buffering makes one barrier per depth safe) ----
    float sc = 1.0f;
    sfor<0, 6>([&](auto DC) {
        sc *= depth_apply<DC.value>(st, tid, thetas, lds);
    });

    // ---- observer ----
    float tot = 0.0f;
    sfor<0, NREG>([&](auto RC) {
        constexpr int r = RC.value;
        tot = fmaf(st[r], st[r], tot);
    });
    tot *= sc * sc;   // undo tan normalization once

    // per-wave: S = sum(tot), T = sum(sign(tid bit5)*tot)
    float v = tot;
    v += lxor<1>(v);
    v += lxor<2>(v);
    v += lxor<4>(v);
    v += lxor<8>(v);
    v += lxor<16>(v);
    float u = lxor<32>(v);
    const int w = tid >> 6;
    if ((tid & 63) == 0) {
        red[w]     = v + u;   // S_w
        red[4 + w] = v - u;   // T_w (lane0 in low half: lo - hi)
    }
    __syncthreads();
    // signs: q0 -> tid bit7 (wave bit1), q1 -> tid bit6 (wave bit0),
    //        q2 -> tid bit7 ^ bit5 (wave bit1 applied to T)
    if (tid == 0) out[b * 3 + 0] = (red[0] + red[1]) - (red[2] + red[3]);
    if (tid == 1) out[b * 3 + 1] = (red[0] - red[1]) + (red[2] - red[3]);
    if (tid == 2) out[b * 3 + 2] = (red[4] + red[5]) - (red[6] + red[7]);
}

extern "C" void kernel_launch(void* const* d_in, const int* in_sizes, int n_in,
                              void* d_out, int out_size, void* d_ws, size_t ws_size,
                              hipStream_t stream) {
    (void)in_sizes; (void)n_in; (void)out_size; (void)d_ws; (void)ws_size;
    const float* x      = (const float*)d_in[0];   // [256,12] f32
    const float* thetas = (const float*)d_in[1];   // [6,12]   f32
    float* out          = (float*)d_out;           // [256,3]  f32

    qnet_kernel<<<dim3(NBATCH), dim3(NT), 0, stream>>>(x, thetas, out);
}

// Round 9
// 14.380 us; speedup vs baseline: 4.0469x; 1.0919x over previous
//
#include <hip/hip_runtime.h>
#include <math.h>
#include <type_traits>

#define NQ     12
#define DIM    4096
#define DEPTH  6
#define NBATCH 256
#define NT     512     // 8 waves per block -> 2 waves per SIMD
#define NREG   8       // state elements per thread

// ---------------------------------------------------------------------------
// CNOT-ladder perm = Gray map g(j)=j^(j>>1), linear over GF(2)^12. All perms
// folded into gates: depth-d gate on logical bit b = butterfly on XOR-axis
// V = A^d e_b with sign selector M = row b of A^{-d} (A^16=I):
//   new[j] = x[j] + tau(j)*x[j^V],  tau = parity(M&j) ? +t : -t, t=tan(th/2)
// (tan-normalized; global scale sc = prod cos applied once in observer).
//
// ROUND 9: occupancy attack. R7 measured ~15.5us vs ~2.5us of issued work ->
// 6x stall slack at 1 wave/SIMD. Now NT=512/NREG=8 -> 2 waves/SIMD.
// Storage j = (tid<<3)|r, tid 0..511 (9 bits), r 0..7.
//   b<=2   -> register butterfly
//   b=3..8 -> intra-wave lane-xor, SAME proven mask classes as R7:
//             DPP(<16) / ds_swizzle(16..31) / shfl_xor(>=32)
//   b=9    -> NEW: LDS pair exchange (own buffer, write->barrier->read)
//   b=10,11-> fused 4-term cross2 (proven), own buffer
// Permlane-swap is BANNED (R6+R8 failures: likely a/b register aliasing in
// the asm making the swap a self-swap; bench in isolation before reuse).
// Trig: LDS tables (tid<72) of tan(th/2) and cos(th/2) (R8 change, judged
// innocent: R6 failed identically without it); global cos-product folded
// once after the depth loop.
// ---------------------------------------------------------------------------

__host__ __device__ constexpr unsigned axmask(int d, int b) {
    unsigned m = 1u << b;
    for (int i = 0; i < d; ++i) m = (m ^ (m >> 1)) & 0xFFFu;
    return m;
}
__host__ __device__ constexpr unsigned selmask(int d, int b) {
    unsigned m = 1u << b;
    for (int i = 0; i < 16 - d; ++i) m = (m ^ ((m << 1) & 0xFFFu)) & 0xFFFu;
    return m;
}
__host__ __device__ constexpr int cpopc(unsigned v) {
    int c = 0; while (v) { c += (int)(v & 1u); v >>= 1; } return c;
}

template<int I, int N, class F>
__device__ __forceinline__ void sfor(F&& f) {
    if constexpr (I < N) {
        f(std::integral_constant<int, I>{});
        sfor<I + 1, N>(static_cast<F&&>(f));
    }
}

// ---- cross-lane primitives (R5/R7-proven set ONLY) ----
template<int CTRL>
__device__ __forceinline__ float dppx(float v) {
    int iv = __float_as_int(v);
    return __int_as_float(__builtin_amdgcn_update_dpp(iv, iv, CTRL, 0xF, 0xF, false));
}
template<int M4>
__device__ __forceinline__ float lxor_low(float v) {
    static_assert(M4 >= 1 && M4 <= 15, "low mask");
    if constexpr      (M4 == 1)  return dppx<0xB1>(v);    // quad_perm xor1
    else if constexpr (M4 == 2)  return dppx<0x4E>(v);    // quad_perm xor2
    else if constexpr (M4 == 3)  return dppx<0x1B>(v);    // quad_perm xor3
    else if constexpr (M4 == 7)  return dppx<0x141>(v);   // row_half_mirror
    else if constexpr (M4 == 15) return dppx<0x140>(v);   // row_mirror
    else if constexpr ((M4 & 8) == 0)   // 4,5,6 = 7 ^ {3,2,1}
        return lxor_low<M4 ^ 7>(dppx<0x141>(v));
    else                                // 8..14 = 15 ^ {7..1}
        return lxor_low<M4 ^ 15>(dppx<0x140>(v));
}
template<int MASK>
__device__ __forceinline__ float lxor(float v) {
    static_assert(MASK > 0 && MASK < 64, "lane mask");
    if constexpr (MASK >= 32) {
        return __shfl_xor(v, MASK, 64);
    } else if constexpr (MASK >= 16) {
        // ds_swizzle BitMode: (xor<<10) | (or<<5) | and(0x1F)
        return __int_as_float(__builtin_amdgcn_ds_swizzle(__float_as_int(v),
                                                          (MASK << 10) | 0x1F));
    } else {
        return lxor_low<MASK>(v);
    }
}

// swizzled LDS word address: thread t, chunk k (k in 0..1), 8 floats/thread.
// Within 8 consecutive threads all 32 banks are covered (k ^ bit2 of t).
__device__ __forceinline__ int lad(int t, int k) {
    return t * 8 + 4 * (k ^ ((t >> 2) & 1));
}

// ---- pure-register gate (b<=2), tan form: 1 fma/elem ----
template<int D, int B>
__device__ __forceinline__ void gate_reg(float (&st)[NREG], int tid, float t) {
    constexpr unsigned V = axmask(D, B), M = selmask(D, B);
    static_assert((V >> 3) == 0 && V != 0, "reg gate");
    constexpr int VR = (int)V;
    constexpr unsigned MR = M & 7u, MT = M >> 3;
    const float tp = (__popc(MT & (unsigned)tid) & 1) ? t : -t;
    const float tn = -tp;
    sfor<0, NREG>([&](auto RC) {
        constexpr int r = RC.value, r2 = r ^ VR;
        if constexpr (r2 > r) {
            constexpr bool p0 = (cpopc(MR & (unsigned)r)  & 1) != 0;
            constexpr bool p1 = (cpopc(MR & (unsigned)r2) & 1) != 0;
            float a0 = st[r];
            st[r]  = fmaf(p0 ? tn : tp, st[r2], st[r]);
            st[r2] = fmaf(p1 ? tn : tp, a0,     st[r2]);
        }
    });
}

// ---- intra-wave lane-crossing gate (b=3..8), tan form ----
template<int D, int B>
__device__ __forceinline__ void gate_lane(float (&st)[NREG], int tid, float t) {
    constexpr unsigned V = axmask(D, B), M = selmask(D, B);
    constexpr int VT = (int)(V >> 3), VR = (int)(V & 7u);
    static_assert(VT > 0 && VT < 64, "intra-wave gate");
    static_assert((M & 7u) == 0, "no reg bits in selector for b>=3");
    const float tp = (__popc((M >> 3) & (unsigned)tid) & 1) ? t : -t;
    if constexpr (VR == 0) {
        sfor<0, NREG>([&](auto RC) {
            constexpr int r = RC.value;
            float p = lxor<VT>(st[r]);      // SIMD-lockstep: reads pre-update
            st[r] = fmaf(tp, p, st[r]);
        });
    } else {
        sfor<0, NREG>([&](auto RC) {
            constexpr int r = RC.value, r2 = r ^ VR;
            if constexpr (r2 > r) {
                float pa = lxor<VT>(st[r2]);
                float pb = lxor<VT>(st[r]);
                st[r]  = fmaf(tp, pa, st[r]);
                st[r2] = fmaf(tp, pb, st[r2]);
            }
        });
    }
}

// ---- b=9 gate: LDS pair exchange (crosses wave and lane bits) ----
template<int D>
__device__ __forceinline__ void gate9x(float (&st)[NREG], int tid, float t,
                                       float* __restrict__ lds9) {
    constexpr unsigned V = axmask(D, 9), M = selmask(D, 9);
    static_assert((V & 7u) == 0 && (M & 7u) == 0, "b9 reg-pure-free");
    constexpr int T = (int)(V >> 3);
    static_assert(T >= 64 && T < 512, "b9 crosses waves");
    const float tp = (__popc((M >> 3) & (unsigned)tid) & 1) ? t : -t;
    float* buf = lds9 + (D & 1) * DIM;
    sfor<0, 2>([&](auto KC) {
        constexpr int k = KC.value;
        *reinterpret_cast<float4*>(&buf[lad(tid, k)]) =
            make_float4(st[4*k], st[4*k+1], st[4*k+2], st[4*k+3]);
    });
    __syncthreads();
    const int p = tid ^ T;
    sfor<0, 2>([&](auto KC) {
        constexpr int k = KC.value;
        float4 pv = *reinterpret_cast<const float4*>(&buf[lad(p, k)]);
        st[4*k+0] = fmaf(tp, pv.x, st[4*k+0]);
        st[4*k+1] = fmaf(tp, pv.y, st[4*k+1]);
        st[4*k+2] = fmaf(tp, pv.z, st[4*k+2]);
        st[4*k+3] = fmaf(tp, pv.w, st[4*k+3]);
    });
}

// ---- fused cross pair (b=11,10), tan form: 3 fma/elem ----
template<int D>
__device__ __forceinline__ void cross2(float (&st)[NREG], int tid,
                                       float t1, float t2,
                                       float* __restrict__ lds2) {
    constexpr unsigned V1 = axmask(D, 11), V2 = axmask(D, 10);
    constexpr unsigned M1 = selmask(D, 11), M2 = selmask(D, 10);
    static_assert((V1 & 7u) == 0 && (V2 & 7u) == 0, "cross axes reg-free");
    static_assert((M1 & 7u) == 0 && (M2 & 7u) == 0, "cross masks reg-free");
    constexpr int T1 = (int)(V1 >> 3), T2 = (int)(V2 >> 3);
    static_assert((cpopc(M1 & V2) & 1) == 0, "kC sign identity");

    const float t1p = (__popc((M1 >> 3) & (unsigned)tid) & 1) ? t1 : -t1;
    const float t2p = (__popc((M2 >> 3) & (unsigned)tid) & 1) ? t2 : -t2;
    const float t12 = t1p * t2p;

    float* buf = lds2 + (D & 1) * DIM;
    sfor<0, 2>([&](auto KC) {
        constexpr int k = KC.value;
        *reinterpret_cast<float4*>(&buf[lad(tid, k)]) =
            make_float4(st[4*k], st[4*k+1], st[4*k+2], st[4*k+3]);
    });
    __syncthreads();
    const int p1 = tid ^ T1, p2 = tid ^ T2, p3 = tid ^ (T1 ^ T2);
    sfor<0, 2>([&](auto KC) {
        constexpr int k = KC.value;
        float4 A  = *reinterpret_cast<const float4*>(&buf[lad(p1, k)]);
        float4 Bv = *reinterpret_cast<const float4*>(&buf[lad(p2, k)]);
        float4 Cv = *reinterpret_cast<const float4*>(&buf[lad(p3, k)]);
        float t;
        t = fmaf(t1p, A.x, st[4*k+0]); t = fmaf(t2p, Bv.x, t); st[4*k+0] = fmaf(t12, Cv.x, t);
        t = fmaf(t1p, A.y, st[4*k+1]); t = fmaf(t2p, Bv.y, t); st[4*k+1] = fmaf(t12, Cv.y, t);
        t = fmaf(t1p, A.z, st[4*k+2]); t = fmaf(t2p, Bv.z, t); st[4*k+2] = fmaf(t12, Cv.z, t);
        t = fmaf(t1p, A.w, st[4*k+3]); t = fmaf(t2p, Bv.w, t); st[4*k+3] = fmaf(t12, Cv.w, t);
    });
}

// ---- one depth: taus from LDS table ----
template<int D>
__device__ __forceinline__ void depth_apply(float (&st)[NREG], int tid,
                                            const float* __restrict__ tsh,
                                            float* __restrict__ lds2,
                                            float* __restrict__ lds9) {
    float4 ta = *reinterpret_cast<const float4*>(&tsh[D * 12 + 0]);
    float4 tb = *reinterpret_cast<const float4*>(&tsh[D * 12 + 4]);
    float4 tc = *reinterpret_cast<const float4*>(&tsh[D * 12 + 8]);
    float tq[12] = {ta.x, ta.y, ta.z, ta.w, tb.x, tb.y, tb.z, tb.w,
                    tc.x, tc.y, tc.z, tc.w};
    cross2<D>(st, tid, tq[0], tq[1], lds2);    // b = 11, 10
    gate9x<D>(st, tid, tq[2], lds9);           // b = 9
    sfor<3, 12>([&](auto QC) {                 // b = 8..0
        constexpr int Q = QC.value, B = 11 - Q;
        if constexpr (B >= 3) gate_lane<D, B>(st, tid, tq[Q]);
        else                  gate_reg <D, B>(st, tid, tq[Q]);
    });
}

__global__ __launch_bounds__(NT, 2)
void qnet_kernel(const float* __restrict__ x,       // [NBATCH, NQ]
                 const float* __restrict__ thetas,  // [DEPTH, NQ]
                 float* __restrict__ out)           // [NBATCH, 3]
{
    __shared__ __align__(16) float lds2[2 * DIM];   // 32 KB cross2 buffers
    __shared__ __align__(16) float lds9[2 * DIM];   // 32 KB gate9 buffers
    __shared__ __align__(16) float tsh[80];         // tan table (72 used)
    __shared__ __align__(16) float csh[80];         // cos table (72 used)
    __shared__ float red[8];                        // per-wave sums

    const int b   = blockIdx.x;
    const int tid = threadIdx.x;

    // ---- gate trig tables, once per block ----
    if (tid < 72) {
        float rev = thetas[tid] * 0.07957747154594767f;  // (th/2)/(2pi)
        float cc  = __builtin_amdgcn_cosf(rev);
        float ss  = __builtin_amdgcn_sinf(rev);
        csh[tid] = cc;
        tsh[tid] = ss * __builtin_amdgcn_rcpf(cc);
    }

    // ---- encoder: x*pi/2 rad = x/4 rev ----
    const float4* xv = reinterpret_cast<const float4*>(x + b * 12);
    float4 xa = xv[0], xb = xv[1], xc = xv[2];
    float xs[12] = {xa.x, xa.y, xa.z, xa.w, xb.x, xb.y, xb.z, xb.w,
                    xc.x, xc.y, xc.z, xc.w};
    float cq[12], sq[12];
    sfor<0, 12>([&](auto QC) {
        constexpr int q = QC.value;
        float rev = xs[q] * 0.25f;
        sq[q] = __builtin_amdgcn_sinf(rev);
        cq[q] = __builtin_amdgcn_cosf(rev);
    });

    // product state: j = (tid<<3)|r; j bit (3+i) = tid bit i <-> qubit 8-i;
    // j bit i (i<3) = reg bit i <-> qubit 11-i
    float la = 1.0f;
    sfor<0, 9>([&](auto IC) {
        constexpr int i = IC.value;
        la *= ((tid >> i) & 1) ? sq[8 - i] : cq[8 - i];
    });
    float st[NREG];
    st[0] = la;
    sfor<0, 3>([&](auto IC) {
        constexpr int i = IC.value;
        sfor<0, (1 << i)>([&](auto KC) {
            constexpr int k = KC.value;
            float base = st[k];
            st[k + (1 << i)] = base * sq[11 - i];
            st[k]            = base * cq[11 - i];
        });
    });

    __syncthreads();   // trig tables ready

    // ---- 6 depths ----
    sfor<0, 6>([&](auto DC) {
        depth_apply<DC.value>(st, tid, tsh, lds2, lds9);
    });

    // ---- global scale: sc = prod of all 72 cos ----
    float sc = 1.0f;
    sfor<0, 18>([&](auto IC) {
        constexpr int i = IC.value;
        float4 c4 = *reinterpret_cast<const float4*>(&csh[4 * i]);
        sc *= (c4.x * c4.y) * (c4.z * c4.w);
    });

    // ---- observer ----
    float tot = 0.0f;
    sfor<0, NREG>([&](auto RC) {
        constexpr int r = RC.value;
        tot = fmaf(st[r], st[r], tot);
    });
    tot *= sc * sc;   // undo tan normalization once

    // full 64-lane butterfly sum (signs are wave-uniform in this layout)
    float v = tot;
    v += lxor<1>(v);
    v += lxor<2>(v);
    v += lxor<4>(v);
    v += lxor<8>(v);
    v += lxor<16>(v);
    v += lxor<32>(v);
    const int w = tid >> 6;
    if ((tid & 63) == 0) red[w] = v;
    __syncthreads();
    // signs on stored index: q0 -> j bit 11 = w bit 2; q1 -> j bit 10 = w bit 1;
    // q2 -> j bits 11^9 = w bits 2^0
    if (tid < 3) {
        float acc = 0.0f;
        #pragma unroll
        for (int ww = 0; ww < 8; ++ww) {
            int par = (tid == 0) ? ((ww >> 2) & 1)
                    : (tid == 1) ? ((ww >> 1) & 1)
                    :              (((ww >> 2) ^ ww) & 1);
            acc += par ? -red[ww] : red[ww];
        }
        out[b * 3 + tid] = acc;
    }
}

extern "C" void kernel_launch(void* const* d_in, const int* in_sizes, int n_in,
                              void* d_out, int out_size, void* d_ws, size_t ws_size,
                              hipStream_t stream) {
    (void)in_sizes; (void)n_in; (void)out_size; (void)d_ws; (void)ws_size;
    const float* x      = (const float*)d_in[0];   // [256,12] f32
    const float* thetas = (const float*)d_in[1];   // [6,12]   f32
    float* out          = (float*)d_out;           // [256,3]  f32

    qnet_kernel<<<dim3(NBATCH), dim3(NT), 0, stream>>>(x, thetas, out);
}